// Round 12
// baseline (22451.778 us; speedup 1.0000x reference)
//
#include <hip/hip_runtime.h>
#include <hip/hip_fp16.h>

// LSTM B=8192 S=1024 H=256 — round 19: gate-stagger v2.
// r18 decomposition: publish-split churn (WRITE +7MB, FETCH +10MB), depth-8
// dependent MFMA chains (MfmaUtil -6%), packed-w0 re-unpack (+96cy). The
// exp2-hoist idea itself was never refuted. v2 fixes all three:
//  - publishes contiguous at substep END (r15 position) -> no line churn
//  - each gate chain split into two depth-4 halves, textually interleaved:
//    2 waves x 2 chains = 4 independent streams/SIMD covers MFMA latency
//    (+4 transient VGPR only)
//  - transport/poll/DMA/barrier = r15 VERBATIM (the only pattern that
//    measures fresh); combine tail (~500cy) covers DMA as r15's EW did
// Moved under MFMA: Ef,Ei,C,Eo = 4 exp2/elem = 32 exp2/wave/substep (~256cy).
// Combine keeps: T=exp2(2.885*clamp(c')), 2 rcp, ~14 VALU per elem.
// Accumulation regroup (init+s0..3)+(s4..7): ~1ulp preact perturbation,
// absmax margin 3.5x. bb[8] funded by packed w0b (r18's trade, kept).
// 256 blocks x 512 thr, 1 block/CU; pairs {B,B^8} share 64 rows = 2 sets.

typedef _Float16 f16x8 __attribute__((ext_vector_type(8)));
typedef float f32x4 __attribute__((ext_vector_type(4)));
typedef unsigned int u32;
typedef unsigned short u16;

#define WINT_OFF 0u
#define W0B_OFF  524288u
#define FLAG_OFF 528384u   // int[256 blocks][2 sets][16] = 32 KB
#define PUB_OFF  1048576u  // u16[(set*2+par)*128+pair][2 half][4096] = 8 MB

static __device__ __forceinline__ float fast_exp2(float x) {
#if __has_builtin(__builtin_amdgcn_exp2f)
  return __builtin_amdgcn_exp2f(x);
#else
  return exp2f(x);
#endif
}
static __device__ __forceinline__ float fast_rcp(float x) {
#if __has_builtin(__builtin_amdgcn_rcpf)
  return __builtin_amdgcn_rcpf(x);
#else
  return 1.0f / x;
#endif
}
static __device__ __forceinline__ u16 f16b(float f) {
  union { _Float16 h; u16 u; } cv; cv.h = (_Float16)f; return cv.u;
}
static __device__ __forceinline__ float h2f(u16 u) {
  union { u16 u; _Float16 h; } cv; cv.u = u; return (float)cv.h;
}
static __device__ __forceinline__ u16* pub_base(u16* pub, int set, int par,
                                                int pid, int half) {
  return pub + ((size_t)(((set * 2 + par) * 128 + pid) * 2 + half) << 12);
}

// Wint[n][k], n = g*256 + j, PRE-SCALED by log2e (x2 for the c gate);
// w0b[n] = packed fp16 {w0*scale, bias*scale}.
__global__ void lstm_prep(const float* __restrict__ Wf, const float* __restrict__ Wi,
                          const float* __restrict__ Wc, const float* __restrict__ Wo,
                          const float* __restrict__ bf_, const float* __restrict__ bi_,
                          const float* __restrict__ bc_, const float* __restrict__ bo_,
                          u16* __restrict__ Wint, u32* __restrict__ w0b) {
  int n = blockIdx.x;       // 0..1023
  int k = threadIdx.x;      // 0..255
  int g = n >> 8, j = n & 255;
  const float* Ws = (g == 0) ? Wf : (g == 1) ? Wi : (g == 2) ? Wc : Wo;
  const float scale = (g == 2) ? 2.88539008f : 1.44269504f;  // 2*log2e : log2e
  Wint[n * 256 + k] = f16b(Ws[j * 257 + 1 + k] * scale);
  if (k == 0) {
    const float* bs = (g == 0) ? bf_ : (g == 1) ? bi_ : (g == 2) ? bc_ : bo_;
    w0b[n] = (u32)f16b(Ws[j * 257] * scale) | ((u32)f16b(bs[j] * scale) << 16);
  }
}

// Zero parity-0 pub of both sets (h_0 = 0), flags, out = bout.
__global__ void lstm_zero(uint4* __restrict__ pub4, uint4* __restrict__ flags4,
                          float* __restrict__ out, const float* __restrict__ bout) {
  int idx = blockIdx.x * 256 + threadIdx.x;
  uint4 z = uint4{0, 0, 0, 0};
  if (idx < 131072) pub4[idx] = z;                 // slot (s0,p0): 2 MB
  else if (idx < 262144) pub4[idx + 131072] = z;   // slot (s1,p0): 2 MB
  else if (idx < 264192) flags4[idx - 262144] = z; // 32 KB flags
  else { int o = idx - 264192; if (o < 8192) out[o] = bout[0]; }
}

__global__ __launch_bounds__(512, 2) void lstm_main(
    const u16* __restrict__ Wint, const u32* __restrict__ w0b,
    const float* __restrict__ x, const float* __restrict__ Wout,
    float* __restrict__ out, u16* __restrict__ pub, int* __restrict__ flags) {

  // [set][parity][0=own k-half,1=peer][32 rows x 128 cols] = 64 KB
  __shared__ __align__(16) u16 stg[2][2][2][4096];

  const int tid  = threadIdx.x;
  const int wv   = tid >> 6;
  const int lane = tid & 63;
  const int l15  = lane & 15;
  const int quad = lane >> 4;
  const int B    = blockIdx.x;
  const int mi   = (B >> 3) & 1;
  const int peer = B ^ 8;
  const int pid  = (B & 7) | ((B >> 4) << 3);   // pair 0..127
  const int rows0 = pid * 64;

  // ---- one-time: W A-fragments (128 regs, STATIC indices) ----
  f16x8 wfrag[4][8];
#pragma unroll
  for (int g = 0; g < 4; ++g)
#pragma unroll
    for (int hm = 0; hm < 2; ++hm)
#pragma unroll
      for (int ktl = 0; ktl < 4; ++ktl) {
        int kbase = (hm == 0 ? mi : 1 - mi) * 128 + ktl * 32;  // runtime, addr only
        wfrag[g][hm * 4 + ktl] = *(const f16x8*)(Wint +
            (size_t)(g * 256 + mi * 128 + wv * 16 + l15) * 256 + kbase + quad * 8);
      }
  // packed w0/bias (16 regs — funds the bb[8] transient block)
  uint4 w0bv[4];
#pragma unroll
  for (int g = 0; g < 4; ++g)
    w0bv[g] = *(const uint4*)(w0b + g * 256 + mi * 128 + wv * 16 + quad * 4);

  // zero stg (h_0 images = 0): 64 KB = 4096 uint4
#pragma unroll
  for (int i = 0; i < 8; ++i) ((uint4*)stg)[tid + i * 512] = uint4{0, 0, 0, 0};

  float cst[2][2][4];   // [set][bt][r]: cell (b = bt*16+l15, j = wv*16+quad*4+r)
#pragma unroll
  for (int s = 0; s < 2; ++s)
#pragma unroll
    for (int bt = 0; bt < 2; ++bt)
#pragma unroll
      for (int r = 0; r < 4; ++r) cst[s][bt][r] = 0.0f;

  const float* xq = x + (size_t)rows0 * 1024;
  float xcur[2][2];
#pragma unroll
  for (int s = 0; s < 2; ++s)
#pragma unroll
    for (int bt = 0; bt < 2; ++bt)
      xcur[s][bt] = xq[(size_t)(s * 32 + bt * 16 + l15) * 1024];

  int* const myflag = flags + B * 32;
  int* const pfl    = flags + peer * 32;

  __syncthreads();

// gate chain, split into two depth-4 halves textually interleaved:
// 2 waves x 2 chains = 4 independent MFMA streams per SIMD (latency covered).
#define GPAIR(G, BT) do {                                                      \
    f32x4 accB_ = {0.0f, 0.0f, 0.0f, 0.0f};                                    \
    _Pragma("unroll")                                                          \
    for (int sl_ = 0; sl_ < 4; ++sl_) {                                        \
      acc[G][BT] = __builtin_amdgcn_mfma_f32_16x16x32_f16(                     \
          wfrag[G][sl_], bb[sl_], acc[G][BT], 0, 0, 0);                        \
      accB_ = __builtin_amdgcn_mfma_f32_16x16x32_f16(                          \
          wfrag[G][sl_ + 4], bb[sl_ + 4], accB_, 0, 0, 0);                     \
    }                                                                          \
    acc[G][BT] += accB_;                                                       \
  } while (0)

// in-place front-end trans on a finished gate accumulator (weaves under the
// NEXT gate's MFMA chains — the r18 idea, minus its publish split)
#define FRONT(G, BT, SGN) do {                                                 \
    _Pragma("unroll")                                                          \
    for (int r_ = 0; r_ < 4; ++r_)                                             \
      acc[G][BT][r_] = fast_exp2((SGN) * acc[G][BT][r_]);                      \
  } while (0)

// load the 8 B-frags for batch-tile BT of set S, parity PAR
#define LOADBB(S, PAR, BT) do {                                                \
    int b_ = (BT) * 16 + l15;                                                  \
    _Pragma("unroll")                                                          \
    for (int sl_ = 0; sl_ < 8; ++sl_) {                                        \
      int cp_ = ((sl_ & 3) * 4 + quad) ^ (b_ & 15);                            \
      bb[sl_] = *(const f16x8*)(&stg[S][PAR][sl_ >> 2][0] + b_ * 128 + cp_ * 8); \
    }                                                                          \
  } while (0)

// combine + publish for batch-tile BT of set S. acc holds Ef,Ei,C,Eo:
//   c' = (c*Y + (C-1)*X) * rcp(X*Y),  X=1+Ef, Y=(1+Ei)(C+1)
//   h  = (T-1) * rcp((1+Eo)(T+1)),    T=exp2(k2*clamp(c',+-40))
#define COMBINE_PUB(S, BT) do {                                                \
    int b_ = (BT) * 16 + l15;                                                  \
    float h0_, h1_, h2_, h3_;                                                  \
    _Pragma("unroll")                                                          \
    for (int r_ = 0; r_ < 4; ++r_) {                                           \
      float Ef_ = acc[0][BT][r_], Ei_ = acc[1][BT][r_];                        \
      float C_  = acc[2][BT][r_], Eo_ = acc[3][BT][r_];                        \
      float X_  = 1.0f + Ef_;                                                  \
      float Y_  = (1.0f + Ei_) * (C_ + 1.0f);                                  \
      float num_ = cst[S][BT][r_] * Y_ + (C_ - 1.0f) * X_;                     \
      float c2_  = num_ * fast_rcp(X_ * Y_);                                   \
      cst[S][BT][r_] = c2_;                                                    \
      float cc_ = fminf(fmaxf(c2_, -40.0f), 40.0f);                            \
      float T_  = fast_exp2(2.88539008f * cc_);                                \
      float hv_ = (T_ - 1.0f) * fast_rcp((1.0f + Eo_) * (T_ + 1.0f));          \
      if (r_ == 0) h0_ = hv_; else if (r_ == 1) h1_ = hv_;                     \
      else if (r_ == 2) h2_ = hv_; else h3_ = hv_;                             \
    }                                                                          \
    u32 lo_ = (u32)f16b(h0_) | ((u32)f16b(h1_) << 16);                         \
    u32 hi_ = (u32)f16b(h2_) | ((u32)f16b(h3_) << 16);                         \
    int c16_ = wv * 2 + (quad >> 1);                                           \
    int off_ = b_ * 128 + (c16_ ^ (b_ & 15)) * 8 + (quad & 1) * 4;             \
    *(uint2*)(lb + off_) = uint2{lo_, hi_};                                    \
    *(uint2*)(pb + off_) = uint2{lo_, hi_};                                    \
  } while (0)

#pragma unroll 1
  for (int t = 0; t < 1024; ++t) {
#pragma unroll
    for (int s = 0; s < 2; ++s) {
      // 1. acc init = x*w0 + bias (packed fp16 pairs, inline unpack)
      f32x4 acc[4][2];
#pragma unroll
      for (int g = 0; g < 4; ++g) {
        u32 pka[4] = {w0bv[g].x, w0bv[g].y, w0bv[g].z, w0bv[g].w};
#pragma unroll
        for (int r = 0; r < 4; ++r) {
          float w0f = h2f((u16)pka[r]), bsf = h2f((u16)(pka[r] >> 16));
          acc[g][0][r] = xcur[s][0] * w0f + bsf;
          acc[g][1][r] = xcur[s][1] * w0f + bsf;
        }
      }
      // x prefetch for (s, t+1) — drained by phase-end barrier
#pragma unroll
      for (int bt = 0; bt < 2; ++bt)
        xcur[s][bt] = xq[(size_t)(s * 32 + bt * 16 + l15) * 1024 + ((t + 1) & 1023)];

      u16* pb = pub_base(pub, s, (t + 1) & 1, pid, mi);
      u16* lb = &stg[s][(t + 1) & 1][0][0];
      f16x8 bb[8];

      // 2. bt0: gate chains (split-2) with front-end exp2 woven between gates
      LOADBB(s, t & 1, 0);
      GPAIR(0, 0);
      GPAIR(1, 0); FRONT(0, 0, -1.0f);   // Ef0 under gateI chains
      GPAIR(2, 0); FRONT(1, 0, -1.0f);   // Ei0 under gateC
      GPAIR(3, 0); FRONT(2, 0,  1.0f);   // C0  under gateO
      FRONT(3, 0, -1.0f);                // Eo0 weaves into bt1's chains

      // 3. bt1: same structure (bb regs reused)
      LOADBB(s, t & 1, 1);
      GPAIR(0, 1);
      GPAIR(1, 1); FRONT(0, 1, -1.0f);
      GPAIR(2, 1); FRONT(1, 1, -1.0f);
      GPAIR(3, 1); FRONT(2, 1,  1.0f);
      FRONT(3, 1, -1.0f);

      // 4. poll at point-of-need + slice DMA of PEER half (r15 verbatim)
      const int tn = (s == 0) ? t : t + 1;
      if (tn < 1024) {
        while (__hip_atomic_load(pfl + (s ^ 1) * 16, __ATOMIC_RELAXED,
                                 __HIP_MEMORY_SCOPE_AGENT) < tn)
          __builtin_amdgcn_s_sleep(1);
        const u16* srcP = pub_base(pub, s ^ 1, tn & 1, pid, 1 - mi);
        __builtin_amdgcn_global_load_lds(
            (const __attribute__((address_space(1))) u32*)(srcP + wv * 512 + lane * 8),
            (__attribute__((address_space(3))) u32*)(&stg[s ^ 1][tn & 1][1][wv * 512]),
            16, 0, 0);
      }

      // 5. combine + publish, contiguous and late (covers DMA; no line churn)
      COMBINE_PUB(s, 0);
      COMBINE_PUB(s, 1);

      // 6. single barrier (drains publish + DMA + x loads + ds_writes) + flag
      __syncthreads();
      if (tid == 0)
        __hip_atomic_store(myflag + s * 16, t + 1, __ATOMIC_RELAXED,
                           __HIP_MEMORY_SCOPE_AGENT);
    }
  }

  // ---- out[b] += (own j-half of h_1024) . Wout  (out pre-set to bout) ----
  if (tid < 64) {
    int s = tid >> 5, b = tid & 31;
    const u16* pbase = pub_base(pub, s, 0, pid, mi);  // parity of t=1024 is 0
    float a = 0.0f;
#pragma unroll
    for (int c = 0; c < 16; ++c) {
      f16x8 hv = *(const f16x8*)(pbase + b * 128 + ((c ^ (b & 15)) * 8));
#pragma unroll
      for (int e = 0; e < 8; ++e) a += (float)hv[e] * Wout[mi * 128 + c * 8 + e];
    }
    atomicAdd(&out[rows0 + s * 32 + b], a);
  }
#undef GPAIR
#undef FRONT
#undef LOADBB
#undef COMBINE_PUB
}

extern "C" void kernel_launch(void* const* d_in, const int* in_sizes, int n_in,
                              void* d_out, int out_size, void* d_ws, size_t ws_size,
                              hipStream_t stream) {
  const float* x    = (const float*)d_in[0];
  const float* Wf   = (const float*)d_in[1];
  const float* bf_  = (const float*)d_in[2];
  const float* Wi   = (const float*)d_in[3];
  const float* bi_  = (const float*)d_in[4];
  const float* Wc   = (const float*)d_in[5];
  const float* bc_  = (const float*)d_in[6];
  const float* Wo   = (const float*)d_in[7];
  const float* bo_  = (const float*)d_in[8];
  const float* Wout = (const float*)d_in[9];
  const float* bout = (const float*)d_in[10];

  u16* Wint  = (u16*)((char*)d_ws + WINT_OFF);
  u32* w0b   = (u32*)((char*)d_ws + W0B_OFF);
  int* flags = (int*)((char*)d_ws + FLAG_OFF);
  u16* pub   = (u16*)((char*)d_ws + PUB_OFF);

  lstm_prep<<<1024, 256, 0, stream>>>(Wf, Wi, Wc, Wo, bf_, bi_, bc_, bo_, Wint, w0b);
  lstm_zero<<<1064, 256, 0, stream>>>((uint4*)pub, (uint4*)flags, (float*)d_out, bout);
  lstm_main<<<256, 512, 0, stream>>>(Wint, w0b, x, Wout, (float*)d_out, pub, flags);
}

// Round 13
// 4624.831 us; speedup vs baseline: 4.8546x; 4.8546x over previous
//
#include <hip/hip_runtime.h>
#include <hip/hip_fp16.h>

// LSTM B=8192 S=1024 H=256 — round 20: RESTORE r15 (best known, 4632 us).
// r19 spilled (FETCH 77GB = scratch traffic; MfmaUtil 7.8%): the GPAIR
// accB_ transients + woven live ranges crossed the VGPR cliff. Search closed:
//  - register ceiling (r19): +8 VGPR live range -> spill catastrophe
//  - poll slack conservation (r9/r11/r12): earlier poll = stale = spin
//  - EW-deferral (r12/r16/r17): delays producer flag by the gained slack;
//    same-region consume needs dup-DMA (L2 thrash, r17) or extra barrier
//  - more phases/sets (r13/r14): fixed barrier cost > recovered overlap
//  - in-wave weave (r18/r19): publish churn or spill
// Structure (proven): 2 staggered sets of 32 rows per pair {B,B^8}; per
// substep [acc-init; K(8 slots); point-of-need poll + peer-half DMA;
// EW(7 trans/elem) + ds_write own half + global publish; barrier; flag].
// stg[set][parity][half] 64KB; weights pre-scaled by log2e (x2 c gate);
// w0/bias unpacked once to f32. 256 blocks x 512 thr, 1 block/CU.

typedef _Float16 f16x8 __attribute__((ext_vector_type(8)));
typedef float f32x4 __attribute__((ext_vector_type(4)));
typedef unsigned int u32;
typedef unsigned short u16;

#define WINT_OFF 0u
#define W0B_OFF  524288u
#define FLAG_OFF 528384u   // int[256 blocks][2 sets][16] = 32 KB
#define PUB_OFF  1048576u  // u16[(set*2+par)*128+pair][2 half][4096] = 8 MB

static __device__ __forceinline__ float fast_exp2(float x) {
#if __has_builtin(__builtin_amdgcn_exp2f)
  return __builtin_amdgcn_exp2f(x);
#else
  return exp2f(x);
#endif
}
static __device__ __forceinline__ float fast_rcp(float x) {
#if __has_builtin(__builtin_amdgcn_rcpf)
  return __builtin_amdgcn_rcpf(x);
#else
  return 1.0f / x;
#endif
}
static __device__ __forceinline__ u16 f16b(float f) {
  union { _Float16 h; u16 u; } cv; cv.h = (_Float16)f; return cv.u;
}
static __device__ __forceinline__ float h2f(u16 u) {
  union { u16 u; _Float16 h; } cv; cv.u = u; return (float)cv.h;
}
static __device__ __forceinline__ u16* pub_base(u16* pub, int set, int par,
                                                int pid, int half) {
  return pub + ((size_t)(((set * 2 + par) * 128 + pid) * 2 + half) << 12);
}

// Wint[n][k], n = g*256 + j, PRE-SCALED by log2e (x2 for the c gate);
// w0b[n] = packed fp16 {w0*scale, bias*scale}.
__global__ void lstm_prep(const float* __restrict__ Wf, const float* __restrict__ Wi,
                          const float* __restrict__ Wc, const float* __restrict__ Wo,
                          const float* __restrict__ bf_, const float* __restrict__ bi_,
                          const float* __restrict__ bc_, const float* __restrict__ bo_,
                          u16* __restrict__ Wint, u32* __restrict__ w0b) {
  int n = blockIdx.x;       // 0..1023
  int k = threadIdx.x;      // 0..255
  int g = n >> 8, j = n & 255;
  const float* Ws = (g == 0) ? Wf : (g == 1) ? Wi : (g == 2) ? Wc : Wo;
  const float scale = (g == 2) ? 2.88539008f : 1.44269504f;  // 2*log2e : log2e
  Wint[n * 256 + k] = f16b(Ws[j * 257 + 1 + k] * scale);
  if (k == 0) {
    const float* bs = (g == 0) ? bf_ : (g == 1) ? bi_ : (g == 2) ? bc_ : bo_;
    w0b[n] = (u32)f16b(Ws[j * 257] * scale) | ((u32)f16b(bs[j] * scale) << 16);
  }
}

// Zero parity-0 pub of both sets (h_0 = 0), flags, out = bout.
__global__ void lstm_zero(uint4* __restrict__ pub4, uint4* __restrict__ flags4,
                          float* __restrict__ out, const float* __restrict__ bout) {
  int idx = blockIdx.x * 256 + threadIdx.x;
  uint4 z = uint4{0, 0, 0, 0};
  if (idx < 131072) pub4[idx] = z;                 // slot (s0,p0): 2 MB
  else if (idx < 262144) pub4[idx + 131072] = z;   // slot (s1,p0): 2 MB
  else if (idx < 264192) flags4[idx - 262144] = z; // 32 KB flags
  else { int o = idx - 264192; if (o < 8192) out[o] = bout[0]; }
}

__global__ __launch_bounds__(512, 2) void lstm_main(
    const u16* __restrict__ Wint, const u32* __restrict__ w0b,
    const float* __restrict__ x, const float* __restrict__ Wout,
    float* __restrict__ out, u16* __restrict__ pub, int* __restrict__ flags) {

  // [set][parity][0=own k-half,1=peer][32 rows x 128 cols] = 64 KB
  __shared__ __align__(16) u16 stg[2][2][2][4096];

  const int tid  = threadIdx.x;
  const int wv   = tid >> 6;
  const int lane = tid & 63;
  const int l15  = lane & 15;
  const int quad = lane >> 4;
  const int B    = blockIdx.x;
  const int mi   = (B >> 3) & 1;
  const int peer = B ^ 8;
  const int pid  = (B & 7) | ((B >> 4) << 3);   // pair 0..127
  const int rows0 = pid * 64;

  // ---- one-time: W A-fragments (128 regs, STATIC indices) ----
  f16x8 wfrag[4][8];
#pragma unroll
  for (int g = 0; g < 4; ++g)
#pragma unroll
    for (int hm = 0; hm < 2; ++hm)
#pragma unroll
      for (int ktl = 0; ktl < 4; ++ktl) {
        int kbase = (hm == 0 ? mi : 1 - mi) * 128 + ktl * 32;  // runtime, addr only
        wfrag[g][hm * 4 + ktl] = *(const f16x8*)(Wint +
            (size_t)(g * 256 + mi * 128 + wv * 16 + l15) * 256 + kbase + quad * 8);
      }
  // one-time unpack of w0/bias to f32 (loop-invariant)
  float w0f[4][4], bsf[4][4];
#pragma unroll
  for (int g = 0; g < 4; ++g) {
    uint4 wv4 = *(const uint4*)(w0b + g * 256 + mi * 128 + wv * 16 + quad * 4);
    u32 pka[4] = {wv4.x, wv4.y, wv4.z, wv4.w};
#pragma unroll
    for (int r = 0; r < 4; ++r) {
      w0f[g][r] = h2f((u16)pka[r]);
      bsf[g][r] = h2f((u16)(pka[r] >> 16));
    }
  }

  // zero stg (h_0 images = 0): 64 KB = 4096 uint4
#pragma unroll
  for (int i = 0; i < 8; ++i) ((uint4*)stg)[tid + i * 512] = uint4{0, 0, 0, 0};

  float cst[2][2][4];   // [set][bt][r]: cell (b = bt*16+l15, j = wv*16+quad*4+r)
#pragma unroll
  for (int s = 0; s < 2; ++s)
#pragma unroll
    for (int bt = 0; bt < 2; ++bt)
#pragma unroll
      for (int r = 0; r < 4; ++r) cst[s][bt][r] = 0.0f;

  const float* xq = x + (size_t)rows0 * 1024;
  float xcur[2][2];
#pragma unroll
  for (int s = 0; s < 2; ++s)
#pragma unroll
    for (int bt = 0; bt < 2; ++bt)
      xcur[s][bt] = xq[(size_t)(s * 32 + bt * 16 + l15) * 1024];

  int* const myflag = flags + B * 32;
  int* const pfl    = flags + peer * 32;

  __syncthreads();

#pragma unroll 1
  for (int t = 0; t < 1024; ++t) {
#pragma unroll
    for (int s = 0; s < 2; ++s) {
      // 1. acc init = x*w0 + bias (pure v_fmac from regs, no stg dependency)
      f32x4 acc[4][2];
#pragma unroll
      for (int g = 0; g < 4; ++g)
#pragma unroll
        for (int r = 0; r < 4; ++r) {
          acc[g][0][r] = xcur[s][0] * w0f[g][r] + bsf[g][r];
          acc[g][1][r] = xcur[s][1] * w0f[g][r] + bsf[g][r];
        }
      // x prefetch for (s, t+1) — drained by phase-end barrier
#pragma unroll
      for (int bt = 0; bt < 2; ++bt)
        xcur[s][bt] = xq[(size_t)(s * 32 + bt * 16 + l15) * 1024 + ((t + 1) & 1023)];

      // 2. K-loop: B-frags from stg[s][t&1] (own half ds_written last step,
      //    peer half DMA'd last substep), 8 MFMA per slot
#pragma unroll
      for (int hm = 0; hm < 2; ++hm)
#pragma unroll
        for (int ktl = 0; ktl < 4; ++ktl) {
          f16x8 bb[2];
#pragma unroll
          for (int bt = 0; bt < 2; ++bt) {
            int b = bt * 16 + l15;
            int cp = (ktl * 4 + quad) ^ (b & 15);
            bb[bt] = *(const f16x8*)(&stg[s][t & 1][hm][0] + b * 128 + cp * 8);
          }
#pragma unroll
          for (int g = 0; g < 4; ++g)
#pragma unroll
            for (int bt = 0; bt < 2; ++bt)
              acc[g][bt] = __builtin_amdgcn_mfma_f32_16x16x32_f16(
                  wfrag[g][hm * 4 + ktl], bb[bt], acc[g][bt], 0, 0, 0);
        }

      // 3. poll at point-of-need + DMA of PEER half only for set s^1's next
      //    consumption (peer's flag store lands just before we first load it)
      const int tn = (s == 0) ? t : t + 1;   // step whose h we fetch for set s^1
      if (tn < 1024) {
        while (__hip_atomic_load(pfl + (s ^ 1) * 16, __ATOMIC_RELAXED,
                                 __HIP_MEMORY_SCOPE_AGENT) < tn)
          __builtin_amdgcn_s_sleep(1);
        const u16* srcP = pub_base(pub, s ^ 1, tn & 1, pid, 1 - mi);
        __builtin_amdgcn_global_load_lds(
            (const __attribute__((address_space(1))) u32*)(srcP + wv * 512 + lane * 8),
            (__attribute__((address_space(3))) u32*)(&stg[s ^ 1][tn & 1][1][wv * 512]),
            16, 0, 0);
      }

      // 4. elementwise + publish: ds_write own half (next parity) + global
      //    publish for the peer. Preacts PRE-SCALED by log2e (k2 for c gate):
      //      c' = (c*Y + (C-1)*X) * rcp(X*Y),  X=1+Ef, Y=(1+Ei)(C+1)
      //      h  = (T-1) * rcp((1+Eo)(T+1)),    T=exp2(k2*clamp(c',+-40))
      u16* pb = pub_base(pub, s, (t + 1) & 1, pid, mi);
      u16* lb = &stg[s][(t + 1) & 1][0][0];
#pragma unroll
      for (int bt = 0; bt < 2; ++bt) {
        int b = bt * 16 + l15;
        u32 lo, hi;
        {
          float h0, h1, h2, h3;
#pragma unroll
          for (int r = 0; r < 4; ++r) {
            float fg = acc[0][bt][r], ig = acc[1][bt][r];
            float cg = acc[2][bt][r], og = acc[3][bt][r];
            float Ef = fast_exp2(-fg);
            float Ei = fast_exp2(-ig);
            float C  = fast_exp2(cg);
            float X  = 1.0f + Ef;
            float Y  = (1.0f + Ei) * (C + 1.0f);
            float num = cst[s][bt][r] * Y + (C - 1.0f) * X;
            float c_  = num * fast_rcp(X * Y);
            cst[s][bt][r] = c_;
            float cc = fminf(fmaxf(c_, -40.0f), 40.0f);
            float T  = fast_exp2(2.88539008f * cc);
            float Eo = fast_exp2(-og);
            float hv = (T - 1.0f) * fast_rcp((1.0f + Eo) * (T + 1.0f));
            if (r == 0) h0 = hv; else if (r == 1) h1 = hv;
            else if (r == 2) h2 = hv; else h3 = hv;
          }
          lo = (u32)f16b(h0) | ((u32)f16b(h1) << 16);
          hi = (u32)f16b(h2) | ((u32)f16b(h3) << 16);
        }
        int c16 = wv * 2 + (quad >> 1);
        int off = b * 128 + (c16 ^ (b & 15)) * 8 + (quad & 1) * 4;
        *(uint2*)(lb + off) = uint2{lo, hi};   // LDS own half (for next K(s))
        *(uint2*)(pb + off) = uint2{lo, hi};   // global publish (peer + out)
      }

      // 5. single barrier: drains publish + DMA + x loads (vmcnt) and the
      //    own-half ds_writes (lgkmcnt)
      __syncthreads();
      if (tid == 0)
        __hip_atomic_store(myflag + s * 16, t + 1, __ATOMIC_RELAXED,
                           __HIP_MEMORY_SCOPE_AGENT);
    }
  }

  // ---- out[b] += (own j-half of h_1024) . Wout  (out pre-set to bout) ----
  if (tid < 64) {
    int s = tid >> 5, b = tid & 31;
    const u16* pbase = pub_base(pub, s, 0, pid, mi);  // parity of t=1024 is 0
    float a = 0.0f;
#pragma unroll
    for (int c = 0; c < 16; ++c) {
      f16x8 hv = *(const f16x8*)(pbase + b * 128 + ((c ^ (b & 15)) * 8));
#pragma unroll
      for (int e = 0; e < 8; ++e) a += (float)hv[e] * Wout[mi * 128 + c * 8 + e];
    }
    atomicAdd(&out[rows0 + s * 32 + b], a);
  }
}

extern "C" void kernel_launch(void* const* d_in, const int* in_sizes, int n_in,
                              void* d_out, int out_size, void* d_ws, size_t ws_size,
                              hipStream_t stream) {
  const float* x    = (const float*)d_in[0];
  const float* Wf   = (const float*)d_in[1];
  const float* bf_  = (const float*)d_in[2];
  const float* Wi   = (const float*)d_in[3];
  const float* bi_  = (const float*)d_in[4];
  const float* Wc   = (const float*)d_in[5];
  const float* bc_  = (const float*)d_in[6];
  const float* Wo   = (const float*)d_in[7];
  const float* bo_  = (const float*)d_in[8];
  const float* Wout = (const float*)d_in[9];
  const float* bout = (const float*)d_in[10];

  u16* Wint  = (u16*)((char*)d_ws + WINT_OFF);
  u32* w0b   = (u32*)((char*)d_ws + W0B_OFF);
  int* flags = (int*)((char*)d_ws + FLAG_OFF);
  u16* pub   = (u16*)((char*)d_ws + PUB_OFF);

  lstm_prep<<<1024, 256, 0, stream>>>(Wf, Wi, Wc, Wo, bf_, bi_, bc_, bo_, Wint, w0b);
  lstm_zero<<<1064, 256, 0, stream>>>((uint4*)pub, (uint4*)flags, (float*)d_out, bout);
  lstm_main<<<256, 512, 0, stream>>>(Wint, w0b, x, Wout, (float*)d_out, pub, flags);
}